// Round 1
// baseline (3439.878 us; speedup 1.0000x reference)
//
#include <hip/hip_runtime.h>
#include <cmath>

#define D 64

__device__ __forceinline__ float wave_reduce_sum(float v) {
  #pragma unroll
  for (int off = 32; off > 0; off >>= 1) v += __shfl_xor(v, off, 64);
  return v;
}
__device__ __forceinline__ float wave_reduce_max(float v) {
  #pragma unroll
  for (int off = 32; off > 0; off >>= 1) v = fmaxf(v, __shfl_xor(v, off, 64));
  return v;
}

// Layer 1: out[src] += val * feat(dst), feat = users if dst<NU else items[dst-NU]
__global__ void edge_l1(const int* __restrict__ src, const int* __restrict__ dst,
                        const float* __restrict__ vals,
                        const float* __restrict__ userF, const float* __restrict__ itemF,
                        float* __restrict__ out, int nE, int NU) {
  int e = blockIdx.x * 4 + (threadIdx.x >> 6);
  if (e >= nE) return;
  int d = threadIdx.x & 63;
  int s = src[e]; int t = dst[e]; float v = vals[e];
  const float* f = (t < NU) ? (userF + (size_t)t * D) : (itemF + (size_t)(t - NU) * D);
  unsafeAtomicAdd(&out[(size_t)s * D + d], v * f[d]);
}

// Layer 2: out[src] += val * cur[dst]
__global__ void edge_l2(const int* __restrict__ src, const int* __restrict__ dst,
                        const float* __restrict__ vals,
                        const float* __restrict__ cur, float* __restrict__ out, int nE) {
  int e = blockIdx.x * 4 + (threadIdx.x >> 6);
  if (e >= nE) return;
  int d = threadIdx.x & 63;
  int s = src[e]; int t = dst[e]; float v = vals[e];
  unsafeAtomicAdd(&out[(size_t)s * D + d], v * cur[(size_t)t * D + d]);
}

// Gather user representation for the B batch users: ug[b] (+)= (feat+l1+l2)/3
__global__ void fin_user_gather(const float* __restrict__ userF, const float* __restrict__ b1,
                                const float* __restrict__ b2, const int* __restrict__ uid,
                                float* __restrict__ ug, int add) {
  int b = blockIdx.x, d = threadIdx.x;
  int u = uid[b];
  size_t o = (size_t)u * D + d;
  float r = (userF[o] + b1[o] + b2[o]) * (1.f / 3.f);
  if (add) ug[(size_t)b * D + d] += r; else ug[(size_t)b * D + d] = r;
}

// Gather course representation at course_ids: cg[b][j] = (feat+l1+l2)/3
__global__ void fin_course_gather(const float* __restrict__ cF, const float* __restrict__ b1,
                                  const float* __restrict__ b2, const int* __restrict__ cid,
                                  float* __restrict__ cg, int NU) {
  int b = blockIdx.x;
  int j = threadIdx.x >> 6, d = threadIdx.x & 63;
  int c = cid[b * 2 + j];
  size_t o = (size_t)(NU + c) * D + d;
  cg[((size_t)b * 2 + j) * D + d] = (cF[(size_t)c * D + d] + b1[o] + b2[o]) * (1.f / 3.f);
}

// Full item-side representation (exercises): e1[i] = (feat+l1+l2)/3
__global__ void fin_items(const float* __restrict__ iF, const float* __restrict__ b1,
                          const float* __restrict__ b2, float* __restrict__ e1,
                          size_t total, size_t off) {
  size_t i = (size_t)blockIdx.x * blockDim.x + threadIdx.x;
  if (i >= total) return;
  e1[i] = (iF[i] + b1[off + i] + b2[off + i]) * (1.f / 3.f);
}

// Fused: last-row attention + MLP + final dot with course reps. One wave per batch elem.
__global__ __launch_bounds__(64) void attn_final(
    const float* __restrict__ e1, const float* __restrict__ pe,
    const int* __restrict__ seq, const int* __restrict__ mask,
    const float* __restrict__ wq_w, const float* __restrict__ wq_b,
    const float* __restrict__ wk_w, const float* __restrict__ wk_b,
    const float* __restrict__ wv_w, const float* __restrict__ wv_b,
    const float* __restrict__ mlp_w, const float* __restrict__ mlp_b,
    const float* __restrict__ ug, const float* __restrict__ cg,
    float* __restrict__ out, int T) {
  __shared__ float xs[64][D];     // T <= 64
  __shared__ float wks[D * D];
  __shared__ float wvs[D * D];
  __shared__ float ps[D];
  __shared__ float ys[D];
  __shared__ float atts[D];
  int b = blockIdx.x, d = threadIdx.x;

  for (int i = d; i < D * D; i += 64) { wks[i] = wk_w[i]; wvs[i] = wv_w[i]; }
  for (int t = 0; t < T; ++t) {
    int sidx = seq[b * T + t];
    xs[t][d] = e1[(size_t)sidx * D + d] + pe[t * D + d];
  }
  __syncthreads();

  // q at last timestep (thread d holds q[d])
  float qd = wq_b[d];
  #pragma unroll 4
  for (int j = 0; j < D; ++j) qd = fmaf(xs[T - 1][j], wq_w[j * D + d], qd);
  if (mask[b * T + (T - 1)] == 0) qd = -100000.0f;

  // scores over all T keys; lane t ends up holding score_t
  float my_score = -INFINITY;
  for (int t = 0; t < T; ++t) {
    float kd = wk_b[d];
    #pragma unroll 8
    for (int j = 0; j < D; ++j) kd = fmaf(xs[t][j], wks[j * D + d], kd);
    if (mask[b * T + t] == 0) kd = -100000.0f;
    float s = wave_reduce_sum(qd * kd) * 0.125f;  // /sqrt(64)
    if (d == t) my_score = s;
  }
  // softmax across lanes
  float m = wave_reduce_max(my_score);
  float p = (d < T) ? expf(my_score - m) : 0.f;
  float sum = wave_reduce_sum(p);
  ps[d] = p / sum;
  __syncthreads();

  // y[j] = sum_t p_t * x[t][j];  att = y @ Wv + bv  (since sum_t p_t = 1)
  float yj = 0.f;
  for (int t = 0; t < T; ++t) yj = fmaf(ps[t], xs[t][d], yj);
  ys[d] = yj;
  __syncthreads();
  float ad = wv_b[d];
  #pragma unroll 8
  for (int j = 0; j < D; ++j) ad = fmaf(ys[j], wvs[j * D + d], ad);
  atts[d] = ad;
  __syncthreads();

  // u_final = relu([u, att] @ mlp_w + mlp_b)
  float h = mlp_b[d];
  #pragma unroll 4
  for (int j = 0; j < D; ++j) h = fmaf(ug[(size_t)b * D + j], mlp_w[j * D + d], h);
  #pragma unroll 4
  for (int j = 0; j < D; ++j) h = fmaf(atts[j], mlp_w[(D + j) * D + d], h);
  h = fmaxf(h, 0.f);

  // out[b,c] = dot(u_final, cg[b,c])
  #pragma unroll
  for (int c = 0; c < 2; ++c) {
    float s = wave_reduce_sum(h * cg[((size_t)b * 2 + c) * D + d]);
    if (d == 0) out[b * 2 + c] = s;
  }
}

extern "C" void kernel_launch(void* const* d_in, const int* in_sizes, int n_in,
                              void* d_out, int out_size, void* d_ws, size_t ws_size,
                              hipStream_t stream) {
  const float* usersF   = (const float*)d_in[0];
  const float* coursesF = (const float*)d_in[1];
  const float* exF      = (const float*)d_in[2];
  const float* knF      = (const float*)d_in[3];
  const float* wq_w = (const float*)d_in[4];
  const float* wq_b = (const float*)d_in[5];
  const float* wk_w = (const float*)d_in[6];
  const float* wk_b = (const float*)d_in[7];
  const float* wv_w = (const float*)d_in[8];
  const float* wv_b = (const float*)d_in[9];
  const float* mlp_w = (const float*)d_in[10];
  const float* mlp_b = (const float*)d_in[11];
  const float* pe = (const float*)d_in[12];
  const float* uc_vals = (const float*)d_in[13];
  const float* ue_vals = (const float*)d_in[14];
  const float* uk_vals = (const float*)d_in[15];
  const int* uc_src = (const int*)d_in[16];
  const int* uc_dst = (const int*)d_in[17];
  const int* ue_src = (const int*)d_in[18];
  const int* ue_dst = (const int*)d_in[19];
  const int* uk_src = (const int*)d_in[20];
  const int* uk_dst = (const int*)d_in[21];
  const int* mask = (const int*)d_in[22];
  const int* seq  = (const int*)d_in[23];
  const int* uid  = (const int*)d_in[24];
  const int* cid  = (const int*)d_in[25];

  int NU = in_sizes[0] / D;
  int NC = in_sizes[1] / D;
  int NE = in_sizes[2] / D;
  int NK = in_sizes[3] / D;
  int B  = in_sizes[24];
  int T  = in_sizes[22] / B;
  int nUC = in_sizes[13], nUE = in_sizes[14], nUK = in_sizes[15];

  int nbmax = NC > NE ? NC : NE; nbmax = nbmax > NK ? nbmax : NK;
  size_t nmax = (size_t)NU + (size_t)nbmax;
  float* buf1 = (float*)d_ws;
  float* buf2 = buf1 + nmax * D;
  float* e1   = buf2 + nmax * D;
  float* ug   = e1 + (size_t)NE * D;
  float* cg   = ug + (size_t)B * D;
  float* out  = (float*)d_out;

  auto eg = [](int n) { return dim3((unsigned)((n + 3) / 4)); };

  // ---- graph uc (users-courses): produces ug (=), cg ----
  size_t szUC = ((size_t)NU + NC) * D * sizeof(float);
  hipMemsetAsync(buf1, 0, szUC, stream);
  hipMemsetAsync(buf2, 0, szUC, stream);
  edge_l1<<<eg(nUC), 256, 0, stream>>>(uc_src, uc_dst, uc_vals, usersF, coursesF, buf1, nUC, NU);
  edge_l2<<<eg(nUC), 256, 0, stream>>>(uc_src, uc_dst, uc_vals, buf1, buf2, nUC);
  fin_user_gather<<<B, 64, 0, stream>>>(usersF, buf1, buf2, uid, ug, 0);
  fin_course_gather<<<B, 128, 0, stream>>>(coursesF, buf1, buf2, cid, cg, NU);

  // ---- graph ue (users-exercises): produces ug (+=), e1 ----
  size_t szUE = ((size_t)NU + NE) * D * sizeof(float);
  hipMemsetAsync(buf1, 0, szUE, stream);
  hipMemsetAsync(buf2, 0, szUE, stream);
  edge_l1<<<eg(nUE), 256, 0, stream>>>(ue_src, ue_dst, ue_vals, usersF, exF, buf1, nUE, NU);
  edge_l2<<<eg(nUE), 256, 0, stream>>>(ue_src, ue_dst, ue_vals, buf1, buf2, nUE);
  fin_user_gather<<<B, 64, 0, stream>>>(usersF, buf1, buf2, uid, ug, 1);
  {
    size_t total = (size_t)NE * D;
    fin_items<<<(unsigned)((total + 255) / 256), 256, 0, stream>>>(
        exF, buf1, buf2, e1, total, (size_t)NU * D);
  }

  // ---- graph uk (users-knowledge): produces ug (+=) ----
  size_t szUK = ((size_t)NU + NK) * D * sizeof(float);
  hipMemsetAsync(buf1, 0, szUK, stream);
  hipMemsetAsync(buf2, 0, szUK, stream);
  edge_l1<<<eg(nUK), 256, 0, stream>>>(uk_src, uk_dst, uk_vals, usersF, knF, buf1, nUK, NU);
  edge_l2<<<eg(nUK), 256, 0, stream>>>(uk_src, uk_dst, uk_vals, buf1, buf2, nUK);
  fin_user_gather<<<B, 64, 0, stream>>>(usersF, buf1, buf2, uid, ug, 1);

  // ---- fused attention + MLP + output ----
  attn_final<<<B, 64, 0, stream>>>(e1, pe, seq, mask, wq_w, wq_b, wk_w, wk_b,
                                   wv_w, wv_b, mlp_w, mlp_b, ug, cg, out, T);
}